// Round 3
// baseline (154.780 us; speedup 1.0000x reference)
//
#include <hip/hip_runtime.h>

typedef __attribute__((ext_vector_type(8))) short short8;
typedef __attribute__((ext_vector_type(4))) float f32x4;

#define NB   16
#define TENC 512
#define DCH  256
#define TMEL 4096
#define ROWS (NB*TENC)   // 8192

__device__ __forceinline__ unsigned short f2bf(float f){
  unsigned u = __builtin_bit_cast(unsigned, f);
  u += 0x7FFFu + ((u >> 16) & 1u);
  return (unsigned short)(u >> 16);
}

// ================= kernel A: scan (blocks 0..15) + x->bf16 cast
// (blocks 16..4111) + weight pack (blocks 4112..4879) =================
__global__ __launch_bounds__(256) void prep_scan_kernel(
    const float* __restrict__ x, const int* __restrict__ target,
    const float* __restrict__ w1, const float* __restrict__ w2,
    unsigned* __restrict__ xb32,
    unsigned short* __restrict__ w1p, unsigned short* __restrict__ w2p,
    int* __restrict__ cum, int* __restrict__ total){
  __shared__ int wsum[4];
  int bid = blockIdx.x, tid = threadIdx.x;
  if (bid < 16){
    int lane = tid & 63, wv = tid >> 6;
    int a0 = target[bid * 512 + 2 * tid];
    int a1 = target[bid * 512 + 2 * tid + 1];
    int ps = a0 + a1;
    #pragma unroll
    for (int off = 1; off < 64; off <<= 1){
      int v = __shfl_up(ps, off);
      if (lane >= off) ps += v;
    }
    if (lane == 63) wsum[wv] = ps;
    __syncthreads();
    int add = 0;
    #pragma unroll
    for (int w = 0; w < 4; ++w){ int s = wsum[w]; if (w < wv) add += s; }
    ps += add;
    cum[bid * 512 + 2 * tid]     = ps - a1;
    cum[bid * 512 + 2 * tid + 1] = ps;
    if (tid == 255) total[bid] = ps;
  } else if (bid < 16 + 4096){
    int i = (bid - 16) * 256 + tid;          // handles x[2i], x[2i+1]
    float v0 = x[2 * i], v1 = x[2 * i + 1];
    xb32[i] = (unsigned)f2bf(v0) | ((unsigned)f2bf(v1) << 16);
  } else {
    int i = (bid - 16 - 4096) * 256 + tid;   // 0..196607
    int j = i & 7, lane = (i >> 3) & 63, nt = (i >> 9) & 15, ks = i >> 13;
    int r   = ks * 32 + ((lane >> 4) * 8) + j;
    int col = nt * 16 + (lane & 15);
    w1p[i] = f2bf(w1[r * 256 + col]);
    w2p[i] = f2bf(w2[r * 256 + col]);
  }
}

// ================= kernel B: blocks 0..255 fused conv1+conv2 (+dur),
// blocks 256..16639 length-regulator rows =================
__global__ __launch_bounds__(256) void mega_kernel(
    const float* __restrict__ x,
    const int* __restrict__ cum, const int* __restrict__ total,
    const unsigned short* __restrict__ xb,
    const unsigned short* __restrict__ w1p, const unsigned short* __restrict__ w2p,
    const float* __restrict__ b1, const float* __restrict__ g1, const float* __restrict__ be1,
    const float* __restrict__ b2, const float* __restrict__ g2, const float* __restrict__ be2,
    const float* __restrict__ wl, const float* __restrict__ bl,
    float* __restrict__ out0, float* __restrict__ alignp, float* __restrict__ durp)
{
  __shared__ unsigned short hsw[64 * 256];   // swizzled h tile, 32 KB
  __shared__ float red[64][4][2];
  __shared__ float dred[32][4];
  int tid = threadIdx.x;

  if (blockIdx.x >= 256){
    // ---------------- length regulator ----------------
    int row  = (blockIdx.x - 256) * 4 + (tid >> 6);
    int lane = tid & 63;
    int b = row >> 12, t = row & 4095;
    size_t orow = (size_t)row * 256;
    size_t arow = (size_t)row * 512;
    int tot = total[b];
    float4 z = {0.f, 0.f, 0.f, 0.f};
    if (t >= tot){
      *reinterpret_cast<float4*>(out0 + orow + lane * 4) = z;
      *reinterpret_cast<float4*>(alignp + arow + lane * 8) = z;
      *reinterpret_cast<float4*>(alignp + arow + lane * 8 + 4) = z;
      return;
    }
    const int* cb = cum + b * 512;
    int lo = 0, hi = 511;
    while (lo < hi){ int mid = (lo + hi) >> 1; if (cb[mid] > t) hi = mid; else lo = mid + 1; }
    const float4 v = *reinterpret_cast<const float4*>(x + ((size_t)b * TENC + lo) * DCH + lane * 4);
    *reinterpret_cast<float4*>(out0 + orow + lane * 4) = v;
    float4 a0 = z, a1 = z;
    int rel = lo - lane * 8;
    if (rel >= 0 && rel < 8){
      if (rel < 4) (&a0.x)[rel] = 1.0f; else (&a1.x)[rel - 4] = 1.0f;
    }
    *reinterpret_cast<float4*>(alignp + arow + lane * 8) = a0;
    *reinterpret_cast<float4*>(alignp + arow + lane * 8 + 4) = a1;
    return;
  }

  // ---------------- fused conv block: output rows [m0, m0+32) ----------------
  int m0 = blockIdx.x * 32;
  int rowlo = (m0 >> 9) << 9, rowhi = rowlo + 512;   // batch row range
  int wave = tid >> 6, l = tid & 63, kgrp = l >> 4, l16 = l & 15;
  int colb = wave * 64 + l16;

  // ---- phase 1: conv1+LN+relu for h rows g = m0-16 .. m0+47 (4 tiles) ----
  f32x4 acc[4][4];
  #pragma unroll
  for (int mt = 0; mt < 4; ++mt)
    #pragma unroll
    for (int nt = 0; nt < 4; ++nt) acc[mt][nt] = (f32x4)0.0f;

  for (int ks = 0; ks < 24; ++ks){
    int shift = ks >> 3;
    int c = (ks & 7) * 32 + kgrp * 8;
    const unsigned short* wb = w1p + (size_t)(ks * 16 + wave * 4) * 512 + l * 8;
    short8 bf0 = *reinterpret_cast<const short8*>(wb);
    short8 bf1 = *reinterpret_cast<const short8*>(wb + 512);
    short8 bf2 = *reinterpret_cast<const short8*>(wb + 1024);
    short8 bf3 = *reinterpret_cast<const short8*>(wb + 1536);
    #pragma unroll
    for (int mt = 0; mt < 4; ++mt){
      int grow = m0 - 16 + mt * 16 + l16 + shift - 1;
      short8 a = {0,0,0,0,0,0,0,0};
      if (grow >= rowlo && grow < rowhi)
        a = *reinterpret_cast<const short8*>(xb + (size_t)grow * 256 + c);
      acc[mt][0] = __builtin_amdgcn_mfma_f32_16x16x32_bf16(a, bf0, acc[mt][0], 0, 0, 0);
      acc[mt][1] = __builtin_amdgcn_mfma_f32_16x16x32_bf16(a, bf1, acc[mt][1], 0, 0, 0);
      acc[mt][2] = __builtin_amdgcn_mfma_f32_16x16x32_bf16(a, bf2, acc[mt][2], 0, 0, 0);
      acc[mt][3] = __builtin_amdgcn_mfma_f32_16x16x32_bf16(a, bf3, acc[mt][3], 0, 0, 0);
    }
  }
  // LN stats per h row
  #pragma unroll
  for (int mt = 0; mt < 4; ++mt){
    float s1[4] = {0,0,0,0}, s2[4] = {0,0,0,0};
    #pragma unroll
    for (int nt = 0; nt < 4; ++nt){
      float bv = b1[colb + nt * 16];
      #pragma unroll
      for (int q = 0; q < 4; ++q){
        float v = acc[mt][nt][q] + bv;
        acc[mt][nt][q] = v;
        s1[q] += v; s2[q] += v * v;
      }
    }
    #pragma unroll
    for (int m = 1; m < 16; m <<= 1)
      #pragma unroll
      for (int q = 0; q < 4; ++q){
        s1[q] += __shfl_xor(s1[q], m);
        s2[q] += __shfl_xor(s2[q], m);
      }
    if (l16 == 0)
      #pragma unroll
      for (int q = 0; q < 4; ++q){
        red[mt * 16 + kgrp * 4 + q][wave][0] = s1[q];
        red[mt * 16 + kgrp * 4 + q][wave][1] = s2[q];
      }
  }
  __syncthreads();
  float mu[4][4], rs[4][4];
  #pragma unroll
  for (int mt = 0; mt < 4; ++mt)
    #pragma unroll
    for (int q = 0; q < 4; ++q){
      int r = mt * 16 + kgrp * 4 + q;
      float S1 = red[r][0][0] + red[r][1][0] + red[r][2][0] + red[r][3][0];
      float S2 = red[r][0][1] + red[r][1][1] + red[r][2][1] + red[r][3][1];
      float m_ = S1 * (1.0f / 256.0f);
      float var = S2 * (1.0f / 256.0f) - m_ * m_;
      mu[mt][q] = m_;
      rs[mt][q] = rsqrtf(var + 1e-5f);
    }
  // write h into swizzled LDS (rows outside this batch -> 0)
  #pragma unroll
  for (int mt = 0; mt < 4; ++mt)
    #pragma unroll
    for (int nt = 0; nt < 4; ++nt){
      int col = colb + nt * 16;
      float g = g1[col], be = be1[col];
      #pragma unroll
      for (int q = 0; q < 4; ++q){
        int r = mt * 16 + kgrp * 4 + q;
        int gq = m0 - 16 + r;
        float y = fmaxf((acc[mt][nt][q] - mu[mt][q]) * rs[mt][q] * g + be, 0.0f);
        unsigned short hv = (gq >= rowlo && gq < rowhi) ? f2bf(y) : (unsigned short)0;
        hsw[r * 256 + (col ^ ((r & 7) << 3))] = hv;
      }
    }
  __syncthreads();

  // ---- phase 2: conv2 (A from LDS) + LN + relu + dot(wl) + exp ----
  f32x4 acc2[2][4];
  #pragma unroll
  for (int mt = 0; mt < 2; ++mt)
    #pragma unroll
    for (int nt = 0; nt < 4; ++nt) acc2[mt][nt] = (f32x4)0.0f;

  for (int ks = 0; ks < 24; ++ks){
    int shift = ks >> 3;
    int c = (ks & 7) * 32 + kgrp * 8;
    const unsigned short* wb = w2p + (size_t)(ks * 16 + wave * 4) * 512 + l * 8;
    short8 bf0 = *reinterpret_cast<const short8*>(wb);
    short8 bf1 = *reinterpret_cast<const short8*>(wb + 512);
    short8 bf2 = *reinterpret_cast<const short8*>(wb + 1024);
    short8 bf3 = *reinterpret_cast<const short8*>(wb + 1536);
    #pragma unroll
    for (int mt = 0; mt < 2; ++mt){
      int rr = 16 + mt * 16 + l16 + shift - 1;   // 15..48, always in LDS tile
      short8 a = *reinterpret_cast<const short8*>(hsw + rr * 256 + (c ^ ((rr & 7) << 3)));
      acc2[mt][0] = __builtin_amdgcn_mfma_f32_16x16x32_bf16(a, bf0, acc2[mt][0], 0, 0, 0);
      acc2[mt][1] = __builtin_amdgcn_mfma_f32_16x16x32_bf16(a, bf1, acc2[mt][1], 0, 0, 0);
      acc2[mt][2] = __builtin_amdgcn_mfma_f32_16x16x32_bf16(a, bf2, acc2[mt][2], 0, 0, 0);
      acc2[mt][3] = __builtin_amdgcn_mfma_f32_16x16x32_bf16(a, bf3, acc2[mt][3], 0, 0, 0);
    }
  }
  __syncthreads();   // red[] reuse safety
  #pragma unroll
  for (int mt = 0; mt < 2; ++mt){
    float s1[4] = {0,0,0,0}, s2[4] = {0,0,0,0};
    #pragma unroll
    for (int nt = 0; nt < 4; ++nt){
      float bv = b2[colb + nt * 16];
      #pragma unroll
      for (int q = 0; q < 4; ++q){
        float v = acc2[mt][nt][q] + bv;
        acc2[mt][nt][q] = v;
        s1[q] += v; s2[q] += v * v;
      }
    }
    #pragma unroll
    for (int m = 1; m < 16; m <<= 1)
      #pragma unroll
      for (int q = 0; q < 4; ++q){
        s1[q] += __shfl_xor(s1[q], m);
        s2[q] += __shfl_xor(s2[q], m);
      }
    if (l16 == 0)
      #pragma unroll
      for (int q = 0; q < 4; ++q){
        red[mt * 16 + kgrp * 4 + q][wave][0] = s1[q];
        red[mt * 16 + kgrp * 4 + q][wave][1] = s2[q];
      }
  }
  __syncthreads();
  float dp[2][4] = {{0,0,0,0},{0,0,0,0}};
  #pragma unroll
  for (int mt = 0; mt < 2; ++mt){
    float mu2[4], rs2[4];
    #pragma unroll
    for (int q = 0; q < 4; ++q){
      int r = mt * 16 + kgrp * 4 + q;
      float S1 = red[r][0][0] + red[r][1][0] + red[r][2][0] + red[r][3][0];
      float S2 = red[r][0][1] + red[r][1][1] + red[r][2][1] + red[r][3][1];
      float m_ = S1 * (1.0f / 256.0f);
      float var = S2 * (1.0f / 256.0f) - m_ * m_;
      mu2[q] = m_;
      rs2[q] = rsqrtf(var + 1e-5f);
    }
    #pragma unroll
    for (int nt = 0; nt < 4; ++nt){
      int col = colb + nt * 16;
      float g = g2[col], be = be2[col], wv = wl[col];
      #pragma unroll
      for (int q = 0; q < 4; ++q){
        float y = fmaxf((acc2[mt][nt][q] - mu2[q]) * rs2[q] * g + be, 0.0f);
        dp[mt][q] += y * wv;
      }
    }
    #pragma unroll
    for (int m = 1; m < 16; m <<= 1)
      #pragma unroll
      for (int q = 0; q < 4; ++q) dp[mt][q] += __shfl_xor(dp[mt][q], m);
    if (l16 == 0)
      #pragma unroll
      for (int q = 0; q < 4; ++q) dred[mt * 16 + kgrp * 4 + q][wave] = dp[mt][q];
  }
  __syncthreads();
  if (tid < 32)
    durp[m0 + tid] = expf(dred[tid][0] + dred[tid][1] + dred[tid][2] + dred[tid][3] + bl[0]);
}

extern "C" void kernel_launch(void* const* d_in, const int* in_sizes, int n_in,
                              void* d_out, int out_size, void* d_ws, size_t ws_size,
                              hipStream_t stream){
  const float* x   = (const float*)d_in[0];
  const int*   target = (const int*)d_in[1];
  const float* w1  = (const float*)d_in[2];
  const float* b1  = (const float*)d_in[3];
  const float* g1  = (const float*)d_in[4];
  const float* be1 = (const float*)d_in[5];
  const float* w2  = (const float*)d_in[6];
  const float* b2  = (const float*)d_in[7];
  const float* g2  = (const float*)d_in[8];
  const float* be2 = (const float*)d_in[9];
  const float* wl  = (const float*)d_in[10];
  const float* bl  = (const float*)d_in[11];

  float* out0   = (float*)d_out;
  float* alignp = out0 + (size_t)NB * TMEL * DCH;
  float* durp   = alignp + (size_t)NB * TMEL * TENC;

  char* ws = (char*)d_ws;
  int* cum   = (int*)ws;                                        // 32 KB
  int* total = (int*)(ws + 32768);
  unsigned short* xb  = (unsigned short*)(ws + 65536);                    // 4 MB
  unsigned short* w1p = (unsigned short*)(ws + 65536 + 4194304);          // 384 KB
  unsigned short* w2p = (unsigned short*)(ws + 65536 + 4194304 + 393216); // 384 KB

  prep_scan_kernel<<<4880, 256, 0, stream>>>(x, target, w1, w2,
      (unsigned*)xb, w1p, w2p, cum, total);
  mega_kernel<<<256 + NB * TMEL / 4, 256, 0, stream>>>(x, cum, total,
      xb, w1p, w2p, b1, g1, be1, b2, g2, be2, wl, bl, out0, alignp, durp);
}

// Round 5
// 115.598 us; speedup vs baseline: 1.3389x; 1.3389x over previous
//
#include <hip/hip_runtime.h>

typedef __attribute__((ext_vector_type(8))) short short8;
typedef __attribute__((ext_vector_type(4))) float f32x4;

#define NB   16
#define TENC 512
#define DCH  256
#define TMEL 4096
#define ROWS (NB*TENC)   // 8192

__device__ __forceinline__ unsigned short f2bf(float f){
  unsigned u = __builtin_bit_cast(unsigned, f);
  u += 0x7FFFu + ((u >> 16) & 1u);
  return (unsigned short)(u >> 16);
}

// ========== kernel A: scan+src-table (blocks 0..15) + x->bf16 cast
// (blocks 16..2063, float4) + weight pack (blocks 2064..2831) ==========
__global__ __launch_bounds__(256) void prep_scan_kernel(
    const float* __restrict__ x, const int* __restrict__ target,
    const float* __restrict__ w1, const float* __restrict__ w2,
    unsigned* __restrict__ xb32,
    unsigned short* __restrict__ w1p, unsigned short* __restrict__ w2p,
    int* __restrict__ cum, int* __restrict__ total, int* __restrict__ src){
  __shared__ int wsum[4];
  __shared__ int stot;
  int bid = blockIdx.x, tid = threadIdx.x;
  if (bid < 16){
    int lane = tid & 63, wv = tid >> 6;
    int a0 = target[bid * 512 + 2 * tid];
    int a1 = target[bid * 512 + 2 * tid + 1];
    int ps = a0 + a1;
    #pragma unroll
    for (int off = 1; off < 64; off <<= 1){
      int v = __shfl_up(ps, off);
      if (lane >= off) ps += v;
    }
    if (lane == 63) wsum[wv] = ps;
    __syncthreads();
    int add = 0;
    #pragma unroll
    for (int w = 0; w < 4; ++w){ int s = wsum[w]; if (w < wv) add += s; }
    ps += add;
    int c1 = ps;            // cum[2tid+1]
    int c0 = ps - a1;       // cum[2tid]
    int cp = c0 - a0;       // cum[2tid-1]
    cum[bid * 512 + 2 * tid]     = c0;
    cum[bid * 512 + 2 * tid + 1] = c1;
    if (tid == 255){ total[bid] = c1; stot = c1; }
    int* sb = src + bid * TMEL;
    for (int t = cp; t < c0; ++t) sb[t] = 2 * tid;
    for (int t = c0; t < c1; ++t) sb[t] = 2 * tid + 1;
    __syncthreads();
    for (int t = stot + tid; t < TMEL; t += 256) sb[t] = -1;
  } else if (bid < 16 + 2048){
    int i = (bid - 16) * 256 + tid;          // handles x[4i..4i+3]
    const f32x4 v = *reinterpret_cast<const f32x4*>(x + 4 * (size_t)i);
    unsigned lo = (unsigned)f2bf(v.x) | ((unsigned)f2bf(v.y) << 16);
    unsigned hi = (unsigned)f2bf(v.z) | ((unsigned)f2bf(v.w) << 16);
    xb32[2 * i]     = lo;
    xb32[2 * i + 1] = hi;
  } else {
    int i = (bid - 16 - 2048) * 256 + tid;   // 0..196607
    int j = i & 7, lane = (i >> 3) & 63, nt = (i >> 9) & 15, ks = i >> 13;
    int r   = ks * 32 + ((lane >> 4) * 8) + j;
    int col = nt * 16 + (lane & 15);
    w1p[i] = f2bf(w1[r * 256 + col]);
    w2p[i] = f2bf(w2[r * 256 + col]);
  }
}

// ========== kernel B: fused conv1+LN+relu -> LDS -> conv2+LN+relu+dot+exp ==========
__global__ __launch_bounds__(256) void conv_fused_kernel(
    const unsigned short* __restrict__ xb,
    const unsigned short* __restrict__ w1p, const unsigned short* __restrict__ w2p,
    const float* __restrict__ b1, const float* __restrict__ g1, const float* __restrict__ be1,
    const float* __restrict__ b2, const float* __restrict__ g2, const float* __restrict__ be2,
    const float* __restrict__ wl, const float* __restrict__ bl,
    float* __restrict__ durp)
{
  __shared__ unsigned short hsw[64 * 256];   // swizzled h tile, 32 KB
  __shared__ float red[64][4][2];
  __shared__ float dred[32][4];
  int tid = threadIdx.x;
  int m0 = blockIdx.x * 32;
  int rowlo = (m0 >> 9) << 9, rowhi = rowlo + 512;
  int wave = tid >> 6, l = tid & 63, kgrp = l >> 4, l16 = l & 15;
  int colb = wave * 64 + l16;

  // ---- phase 1: conv1+LN+relu for h rows g = m0-16 .. m0+47 (4 tiles) ----
  f32x4 acc[4][4];
  #pragma unroll
  for (int mt = 0; mt < 4; ++mt)
    #pragma unroll
    for (int nt = 0; nt < 4; ++nt) acc[mt][nt] = (f32x4)0.0f;

  for (int ks = 0; ks < 24; ++ks){
    int shift = ks >> 3;
    int c = (ks & 7) * 32 + kgrp * 8;
    const unsigned short* wb = w1p + (size_t)(ks * 16 + wave * 4) * 512 + l * 8;
    short8 bf0 = *reinterpret_cast<const short8*>(wb);
    short8 bf1 = *reinterpret_cast<const short8*>(wb + 512);
    short8 bf2 = *reinterpret_cast<const short8*>(wb + 1024);
    short8 bf3 = *reinterpret_cast<const short8*>(wb + 1536);
    #pragma unroll
    for (int mt = 0; mt < 4; ++mt){
      int grow = m0 - 16 + mt * 16 + l16 + shift - 1;
      short8 a = {0,0,0,0,0,0,0,0};
      if (grow >= rowlo && grow < rowhi)
        a = *reinterpret_cast<const short8*>(xb + (size_t)grow * 256 + c);
      acc[mt][0] = __builtin_amdgcn_mfma_f32_16x16x32_bf16(a, bf0, acc[mt][0], 0, 0, 0);
      acc[mt][1] = __builtin_amdgcn_mfma_f32_16x16x32_bf16(a, bf1, acc[mt][1], 0, 0, 0);
      acc[mt][2] = __builtin_amdgcn_mfma_f32_16x16x32_bf16(a, bf2, acc[mt][2], 0, 0, 0);
      acc[mt][3] = __builtin_amdgcn_mfma_f32_16x16x32_bf16(a, bf3, acc[mt][3], 0, 0, 0);
    }
  }
  #pragma unroll
  for (int mt = 0; mt < 4; ++mt){
    float s1[4] = {0,0,0,0}, s2[4] = {0,0,0,0};
    #pragma unroll
    for (int nt = 0; nt < 4; ++nt){
      float bv = b1[colb + nt * 16];
      #pragma unroll
      for (int q = 0; q < 4; ++q){
        float v = acc[mt][nt][q] + bv;
        acc[mt][nt][q] = v;
        s1[q] += v; s2[q] += v * v;
      }
    }
    #pragma unroll
    for (int m = 1; m < 16; m <<= 1)
      #pragma unroll
      for (int q = 0; q < 4; ++q){
        s1[q] += __shfl_xor(s1[q], m);
        s2[q] += __shfl_xor(s2[q], m);
      }
    if (l16 == 0)
      #pragma unroll
      for (int q = 0; q < 4; ++q){
        red[mt * 16 + kgrp * 4 + q][wave][0] = s1[q];
        red[mt * 16 + kgrp * 4 + q][wave][1] = s2[q];
      }
  }
  __syncthreads();
  float mu[4][4], rs[4][4];
  #pragma unroll
  for (int mt = 0; mt < 4; ++mt)
    #pragma unroll
    for (int q = 0; q < 4; ++q){
      int r = mt * 16 + kgrp * 4 + q;
      float S1 = red[r][0][0] + red[r][1][0] + red[r][2][0] + red[r][3][0];
      float S2 = red[r][0][1] + red[r][1][1] + red[r][2][1] + red[r][3][1];
      float m_ = S1 * (1.0f / 256.0f);
      float var = S2 * (1.0f / 256.0f) - m_ * m_;
      mu[mt][q] = m_;
      rs[mt][q] = rsqrtf(var + 1e-5f);
    }
  #pragma unroll
  for (int mt = 0; mt < 4; ++mt)
    #pragma unroll
    for (int nt = 0; nt < 4; ++nt){
      int col = colb + nt * 16;
      float g = g1[col], be = be1[col];
      #pragma unroll
      for (int q = 0; q < 4; ++q){
        int r = mt * 16 + kgrp * 4 + q;
        int gq = m0 - 16 + r;
        float y = fmaxf((acc[mt][nt][q] - mu[mt][q]) * rs[mt][q] * g + be, 0.0f);
        unsigned short hv = (gq >= rowlo && gq < rowhi) ? f2bf(y) : (unsigned short)0;
        hsw[r * 256 + (col ^ ((r & 7) << 3))] = hv;
      }
    }
  __syncthreads();

  // ---- phase 2: conv2 (A from LDS) + LN + relu + dot(wl) + exp ----
  f32x4 acc2[2][4];
  #pragma unroll
  for (int mt = 0; mt < 2; ++mt)
    #pragma unroll
    for (int nt = 0; nt < 4; ++nt) acc2[mt][nt] = (f32x4)0.0f;

  for (int ks = 0; ks < 24; ++ks){
    int shift = ks >> 3;
    int c = (ks & 7) * 32 + kgrp * 8;
    const unsigned short* wb = w2p + (size_t)(ks * 16 + wave * 4) * 512 + l * 8;
    short8 bf0 = *reinterpret_cast<const short8*>(wb);
    short8 bf1 = *reinterpret_cast<const short8*>(wb + 512);
    short8 bf2 = *reinterpret_cast<const short8*>(wb + 1024);
    short8 bf3 = *reinterpret_cast<const short8*>(wb + 1536);
    #pragma unroll
    for (int mt = 0; mt < 2; ++mt){
      int rr = 16 + mt * 16 + l16 + shift - 1;   // 15..48
      short8 a = *reinterpret_cast<const short8*>(hsw + rr * 256 + (c ^ ((rr & 7) << 3)));
      acc2[mt][0] = __builtin_amdgcn_mfma_f32_16x16x32_bf16(a, bf0, acc2[mt][0], 0, 0, 0);
      acc2[mt][1] = __builtin_amdgcn_mfma_f32_16x16x32_bf16(a, bf1, acc2[mt][1], 0, 0, 0);
      acc2[mt][2] = __builtin_amdgcn_mfma_f32_16x16x32_bf16(a, bf2, acc2[mt][2], 0, 0, 0);
      acc2[mt][3] = __builtin_amdgcn_mfma_f32_16x16x32_bf16(a, bf3, acc2[mt][3], 0, 0, 0);
    }
  }
  __syncthreads();
  #pragma unroll
  for (int mt = 0; mt < 2; ++mt){
    float s1[4] = {0,0,0,0}, s2[4] = {0,0,0,0};
    #pragma unroll
    for (int nt = 0; nt < 4; ++nt){
      float bv = b2[colb + nt * 16];
      #pragma unroll
      for (int q = 0; q < 4; ++q){
        float v = acc2[mt][nt][q] + bv;
        acc2[mt][nt][q] = v;
        s1[q] += v; s2[q] += v * v;
      }
    }
    #pragma unroll
    for (int m = 1; m < 16; m <<= 1)
      #pragma unroll
      for (int q = 0; q < 4; ++q){
        s1[q] += __shfl_xor(s1[q], m);
        s2[q] += __shfl_xor(s2[q], m);
      }
    if (l16 == 0)
      #pragma unroll
      for (int q = 0; q < 4; ++q){
        red[mt * 16 + kgrp * 4 + q][wave][0] = s1[q];
        red[mt * 16 + kgrp * 4 + q][wave][1] = s2[q];
      }
  }
  __syncthreads();
  float dp[2][4] = {{0,0,0,0},{0,0,0,0}};
  #pragma unroll
  for (int mt = 0; mt < 2; ++mt){
    float mu2[4], rs2[4];
    #pragma unroll
    for (int q = 0; q < 4; ++q){
      int r = mt * 16 + kgrp * 4 + q;
      float S1 = red[r][0][0] + red[r][1][0] + red[r][2][0] + red[r][3][0];
      float S2 = red[r][0][1] + red[r][1][1] + red[r][2][1] + red[r][3][1];
      float m_ = S1 * (1.0f / 256.0f);
      float var = S2 * (1.0f / 256.0f) - m_ * m_;
      mu2[q] = m_;
      rs2[q] = rsqrtf(var + 1e-5f);
    }
    #pragma unroll
    for (int nt = 0; nt < 4; ++nt){
      int col = colb + nt * 16;
      float g = g2[col], be = be2[col], wv = wl[col];
      #pragma unroll
      for (int q = 0; q < 4; ++q){
        float y = fmaxf((acc2[mt][nt][q] - mu2[q]) * rs2[q] * g + be, 0.0f);
        dp[mt][q] += y * wv;
      }
    }
    #pragma unroll
    for (int m = 1; m < 16; m <<= 1)
      #pragma unroll
      for (int q = 0; q < 4; ++q) dp[mt][q] += __shfl_xor(dp[mt][q], m);
    if (l16 == 0)
      #pragma unroll
      for (int q = 0; q < 4; ++q) dred[mt * 16 + kgrp * 4 + q][wave] = dp[mt][q];
  }
  __syncthreads();
  if (tid < 32)
    durp[m0 + tid] = expf(dred[tid][0] + dred[tid][1] + dred[tid][2] + dred[tid][3] + bl[0]);
}

// ========== kernel C: length regulator, src-table driven, zero LDS ==========
__global__ __launch_bounds__(256) void lr_kernel(const float* __restrict__ x,
    const int* __restrict__ src,
    float* __restrict__ out0, float* __restrict__ alignp){
  int row  = blockIdx.x * 4 + (threadIdx.x >> 6);
  int lane = threadIdx.x & 63;
  int b = row >> 12;
  int s = src[row];
  size_t orow = (size_t)row * 256;
  size_t arow = (size_t)row * 512;
  f32x4 z = {0.f, 0.f, 0.f, 0.f};
  if (s < 0){
    __builtin_nontemporal_store(z, reinterpret_cast<f32x4*>(out0 + orow + lane * 4));
    __builtin_nontemporal_store(z, reinterpret_cast<f32x4*>(alignp + arow + lane * 8));
    __builtin_nontemporal_store(z, reinterpret_cast<f32x4*>(alignp + arow + lane * 8 + 4));
    return;
  }
  const f32x4 v = *reinterpret_cast<const f32x4*>(x + ((size_t)b * TENC + s) * DCH + lane * 4);
  __builtin_nontemporal_store(v, reinterpret_cast<f32x4*>(out0 + orow + lane * 4));
  f32x4 a0 = z, a1 = z;
  int rel = s - lane * 8;
  if (rel >= 0 && rel < 8){
    if (rel < 4) a0[rel] = 1.0f; else a1[rel - 4] = 1.0f;
  }
  __builtin_nontemporal_store(a0, reinterpret_cast<f32x4*>(alignp + arow + lane * 8));
  __builtin_nontemporal_store(a1, reinterpret_cast<f32x4*>(alignp + arow + lane * 8 + 4));
}

extern "C" void kernel_launch(void* const* d_in, const int* in_sizes, int n_in,
                              void* d_out, int out_size, void* d_ws, size_t ws_size,
                              hipStream_t stream){
  const float* x   = (const float*)d_in[0];
  const int*   target = (const int*)d_in[1];
  const float* w1  = (const float*)d_in[2];
  const float* b1  = (const float*)d_in[3];
  const float* g1  = (const float*)d_in[4];
  const float* be1 = (const float*)d_in[5];
  const float* w2  = (const float*)d_in[6];
  const float* b2  = (const float*)d_in[7];
  const float* g2  = (const float*)d_in[8];
  const float* be2 = (const float*)d_in[9];
  const float* wl  = (const float*)d_in[10];
  const float* bl  = (const float*)d_in[11];

  float* out0   = (float*)d_out;
  float* alignp = out0 + (size_t)NB * TMEL * DCH;
  float* durp   = alignp + (size_t)NB * TMEL * TENC;

  char* ws = (char*)d_ws;
  int* cum   = (int*)ws;                                    // 32 KB
  int* total = (int*)(ws + 32768);
  int* src   = (int*)(ws + 65536);                          // 256 KB
  unsigned short* xb  = (unsigned short*)(ws + 65536 + 262144);            // 4 MB
  unsigned short* w1p = (unsigned short*)(ws + 65536 + 262144 + 4194304);  // 384 KB
  unsigned short* w2p = (unsigned short*)(ws + 65536 + 262144 + 4194304 + 393216);

  prep_scan_kernel<<<2832, 256, 0, stream>>>(x, target, w1, w2,
      (unsigned*)xb, w1p, w2p, cum, total, src);
  conv_fused_kernel<<<256, 256, 0, stream>>>(xb, w1p, w2p,
      b1, g1, be1, b2, g2, be2, wl, bl, durp);
  lr_kernel<<<NB * TMEL / 4, 256, 0, stream>>>(x, src, out0, alignp);
}

// Round 6
// 80.239 us; speedup vs baseline: 1.9290x; 1.4407x over previous
//
#include <hip/hip_runtime.h>

typedef __attribute__((ext_vector_type(8))) short short8;
typedef __attribute__((ext_vector_type(4))) float f32x4;

#define NB   16
#define TENC 512
#define DCH  256
#define TMEL 4096
#define ROWS (NB*TENC)   // 8192

__device__ __forceinline__ unsigned short f2bf(float f){
  unsigned u = __builtin_bit_cast(unsigned, f);
  u += 0x7FFFu + ((u >> 16) & 1u);
  return (unsigned short)(u >> 16);
}

// ========== kernel A: scan+src-table (blocks 0..15) + x->bf16 cast
// (blocks 16..2063, float4) + weight pack (blocks 2064..2831) ==========
__global__ __launch_bounds__(256) void prep_scan_kernel(
    const float* __restrict__ x, const int* __restrict__ target,
    const float* __restrict__ w1, const float* __restrict__ w2,
    unsigned* __restrict__ xb32,
    unsigned short* __restrict__ w1p, unsigned short* __restrict__ w2p,
    int* __restrict__ cum, int* __restrict__ total, int* __restrict__ src){
  __shared__ int wsum[4];
  __shared__ int stot;
  int bid = blockIdx.x, tid = threadIdx.x;
  if (bid < 16){
    int lane = tid & 63, wv = tid >> 6;
    int a0 = target[bid * 512 + 2 * tid];
    int a1 = target[bid * 512 + 2 * tid + 1];
    int ps = a0 + a1;
    #pragma unroll
    for (int off = 1; off < 64; off <<= 1){
      int v = __shfl_up(ps, off);
      if (lane >= off) ps += v;
    }
    if (lane == 63) wsum[wv] = ps;
    __syncthreads();
    int add = 0;
    #pragma unroll
    for (int w = 0; w < 4; ++w){ int s = wsum[w]; if (w < wv) add += s; }
    ps += add;
    int c1 = ps;            // cum[2tid+1]
    int c0 = ps - a1;       // cum[2tid]
    int cp = c0 - a0;       // cum[2tid-1]
    cum[bid * 512 + 2 * tid]     = c0;
    cum[bid * 512 + 2 * tid + 1] = c1;
    if (tid == 255){ total[bid] = c1; stot = c1; }
    int* sb = src + bid * TMEL;
    for (int t = cp; t < c0; ++t) sb[t] = 2 * tid;
    for (int t = c0; t < c1; ++t) sb[t] = 2 * tid + 1;
    __syncthreads();
    for (int t = stot + tid; t < TMEL; t += 256) sb[t] = -1;
  } else if (bid < 16 + 2048){
    int i = (bid - 16) * 256 + tid;          // handles x[4i..4i+3]
    const f32x4 v = *reinterpret_cast<const f32x4*>(x + 4 * (size_t)i);
    unsigned lo = (unsigned)f2bf(v.x) | ((unsigned)f2bf(v.y) << 16);
    unsigned hi = (unsigned)f2bf(v.z) | ((unsigned)f2bf(v.w) << 16);
    xb32[2 * i]     = lo;
    xb32[2 * i + 1] = hi;
  } else {
    int i = (bid - 16 - 2048) * 256 + tid;   // 0..196607
    int j = i & 7, lane = (i >> 3) & 63, nt = (i >> 9) & 15, ks = i >> 13;
    int r   = ks * 32 + ((lane >> 4) * 8) + j;
    int col = nt * 16 + (lane & 15);
    w1p[i] = f2bf(w1[r * 256 + col]);
    w2p[i] = f2bf(w2[r * 256 + col]);
  }
}

// ========== kernel B: fused conv1+LN+relu -> LDS -> conv2+LN+relu+dot+exp ==========
// 512 blocks x 16 output rows. Phase1 computes 48 halo h-rows (3 m-tiles).
__global__ __launch_bounds__(256) void conv_fused_kernel(
    const unsigned short* __restrict__ xb,
    const unsigned short* __restrict__ w1p, const unsigned short* __restrict__ w2p,
    const float* __restrict__ b1, const float* __restrict__ g1, const float* __restrict__ be1,
    const float* __restrict__ b2, const float* __restrict__ g2, const float* __restrict__ be2,
    const float* __restrict__ wl, const float* __restrict__ bl,
    float* __restrict__ durp)
{
  __shared__ unsigned short hsw[48 * 256];   // swizzled h tile, 24 KB
  __shared__ float red[48][4][2];
  __shared__ float dred[16][4];
  int tid = threadIdx.x;
  int m0 = blockIdx.x * 16;
  int rowlo = (m0 >> 9) << 9, rowhi = rowlo + 512;
  int wave = tid >> 6, l = tid & 63, kgrp = l >> 4, l16 = l & 15;
  int colb = wave * 64 + l16;

  // ---- phase 1: conv1+LN+relu for h rows g = m0-16 .. m0+31 (3 tiles) ----
  f32x4 acc[3][4];
  #pragma unroll
  for (int mt = 0; mt < 3; ++mt)
    #pragma unroll
    for (int nt = 0; nt < 4; ++nt) acc[mt][nt] = (f32x4)0.0f;

  for (int ks = 0; ks < 24; ++ks){
    int shift = ks >> 3;
    int c = (ks & 7) * 32 + kgrp * 8;
    const unsigned short* wb = w1p + (size_t)(ks * 16 + wave * 4) * 512 + l * 8;
    short8 bf0 = *reinterpret_cast<const short8*>(wb);
    short8 bf1 = *reinterpret_cast<const short8*>(wb + 512);
    short8 bf2 = *reinterpret_cast<const short8*>(wb + 1024);
    short8 bf3 = *reinterpret_cast<const short8*>(wb + 1536);
    #pragma unroll
    for (int mt = 0; mt < 3; ++mt){
      int grow = m0 - 16 + mt * 16 + l16 + shift - 1;
      short8 a = {0,0,0,0,0,0,0,0};
      if (grow >= rowlo && grow < rowhi)
        a = *reinterpret_cast<const short8*>(xb + (size_t)grow * 256 + c);
      acc[mt][0] = __builtin_amdgcn_mfma_f32_16x16x32_bf16(a, bf0, acc[mt][0], 0, 0, 0);
      acc[mt][1] = __builtin_amdgcn_mfma_f32_16x16x32_bf16(a, bf1, acc[mt][1], 0, 0, 0);
      acc[mt][2] = __builtin_amdgcn_mfma_f32_16x16x32_bf16(a, bf2, acc[mt][2], 0, 0, 0);
      acc[mt][3] = __builtin_amdgcn_mfma_f32_16x16x32_bf16(a, bf3, acc[mt][3], 0, 0, 0);
    }
  }
  #pragma unroll
  for (int mt = 0; mt < 3; ++mt){
    float s1[4] = {0,0,0,0}, s2[4] = {0,0,0,0};
    #pragma unroll
    for (int nt = 0; nt < 4; ++nt){
      float bv = b1[colb + nt * 16];
      #pragma unroll
      for (int q = 0; q < 4; ++q){
        float v = acc[mt][nt][q] + bv;
        acc[mt][nt][q] = v;
        s1[q] += v; s2[q] += v * v;
      }
    }
    #pragma unroll
    for (int m = 1; m < 16; m <<= 1)
      #pragma unroll
      for (int q = 0; q < 4; ++q){
        s1[q] += __shfl_xor(s1[q], m);
        s2[q] += __shfl_xor(s2[q], m);
      }
    if (l16 == 0)
      #pragma unroll
      for (int q = 0; q < 4; ++q){
        red[mt * 16 + kgrp * 4 + q][wave][0] = s1[q];
        red[mt * 16 + kgrp * 4 + q][wave][1] = s2[q];
      }
  }
  __syncthreads();
  float mu[3][4], rs[3][4];
  #pragma unroll
  for (int mt = 0; mt < 3; ++mt)
    #pragma unroll
    for (int q = 0; q < 4; ++q){
      int r = mt * 16 + kgrp * 4 + q;
      float S1 = red[r][0][0] + red[r][1][0] + red[r][2][0] + red[r][3][0];
      float S2 = red[r][0][1] + red[r][1][1] + red[r][2][1] + red[r][3][1];
      float m_ = S1 * (1.0f / 256.0f);
      float var = S2 * (1.0f / 256.0f) - m_ * m_;
      mu[mt][q] = m_;
      rs[mt][q] = rsqrtf(var + 1e-5f);
    }
  #pragma unroll
  for (int mt = 0; mt < 3; ++mt)
    #pragma unroll
    for (int nt = 0; nt < 4; ++nt){
      int col = colb + nt * 16;
      float g = g1[col], be = be1[col];
      #pragma unroll
      for (int q = 0; q < 4; ++q){
        int r = mt * 16 + kgrp * 4 + q;
        int gq = m0 - 16 + r;
        float y = fmaxf((acc[mt][nt][q] - mu[mt][q]) * rs[mt][q] * g + be, 0.0f);
        unsigned short hv = (gq >= rowlo && gq < rowhi) ? f2bf(y) : (unsigned short)0;
        hsw[r * 256 + (col ^ ((r & 7) << 3))] = hv;
      }
    }
  __syncthreads();

  // ---- phase 2: conv2 (A from LDS) + LN + relu + dot(wl) + exp ----
  f32x4 acc2[4];
  #pragma unroll
  for (int nt = 0; nt < 4; ++nt) acc2[nt] = (f32x4)0.0f;

  for (int ks = 0; ks < 24; ++ks){
    int shift = ks >> 3;
    int c = (ks & 7) * 32 + kgrp * 8;
    const unsigned short* wb = w2p + (size_t)(ks * 16 + wave * 4) * 512 + l * 8;
    short8 bf0 = *reinterpret_cast<const short8*>(wb);
    short8 bf1 = *reinterpret_cast<const short8*>(wb + 512);
    short8 bf2 = *reinterpret_cast<const short8*>(wb + 1024);
    short8 bf3 = *reinterpret_cast<const short8*>(wb + 1536);
    int rr = 16 + l16 + shift - 1;   // 15..31, inside 48-row tile
    short8 a = *reinterpret_cast<const short8*>(hsw + rr * 256 + (c ^ ((rr & 7) << 3)));
    acc2[0] = __builtin_amdgcn_mfma_f32_16x16x32_bf16(a, bf0, acc2[0], 0, 0, 0);
    acc2[1] = __builtin_amdgcn_mfma_f32_16x16x32_bf16(a, bf1, acc2[1], 0, 0, 0);
    acc2[2] = __builtin_amdgcn_mfma_f32_16x16x32_bf16(a, bf2, acc2[2], 0, 0, 0);
    acc2[3] = __builtin_amdgcn_mfma_f32_16x16x32_bf16(a, bf3, acc2[3], 0, 0, 0);
  }
  __syncthreads();
  {
    float s1[4] = {0,0,0,0}, s2[4] = {0,0,0,0};
    #pragma unroll
    for (int nt = 0; nt < 4; ++nt){
      float bv = b2[colb + nt * 16];
      #pragma unroll
      for (int q = 0; q < 4; ++q){
        float v = acc2[nt][q] + bv;
        acc2[nt][q] = v;
        s1[q] += v; s2[q] += v * v;
      }
    }
    #pragma unroll
    for (int m = 1; m < 16; m <<= 1)
      #pragma unroll
      for (int q = 0; q < 4; ++q){
        s1[q] += __shfl_xor(s1[q], m);
        s2[q] += __shfl_xor(s2[q], m);
      }
    if (l16 == 0)
      #pragma unroll
      for (int q = 0; q < 4; ++q){
        red[kgrp * 4 + q][wave][0] = s1[q];
        red[kgrp * 4 + q][wave][1] = s2[q];
      }
  }
  __syncthreads();
  {
    float mu2[4], rs2[4];
    #pragma unroll
    for (int q = 0; q < 4; ++q){
      int r = kgrp * 4 + q;
      float S1 = red[r][0][0] + red[r][1][0] + red[r][2][0] + red[r][3][0];
      float S2 = red[r][0][1] + red[r][1][1] + red[r][2][1] + red[r][3][1];
      float m_ = S1 * (1.0f / 256.0f);
      float var = S2 * (1.0f / 256.0f) - m_ * m_;
      mu2[q] = m_;
      rs2[q] = rsqrtf(var + 1e-5f);
    }
    float dp[4] = {0,0,0,0};
    #pragma unroll
    for (int nt = 0; nt < 4; ++nt){
      int col = colb + nt * 16;
      float g = g2[col], be = be2[col], wv = wl[col];
      #pragma unroll
      for (int q = 0; q < 4; ++q){
        float y = fmaxf((acc2[nt][q] - mu2[q]) * rs2[q] * g + be, 0.0f);
        dp[q] += y * wv;
      }
    }
    #pragma unroll
    for (int m = 1; m < 16; m <<= 1)
      #pragma unroll
      for (int q = 0; q < 4; ++q) dp[q] += __shfl_xor(dp[q], m);
    if (l16 == 0)
      #pragma unroll
      for (int q = 0; q < 4; ++q) dred[kgrp * 4 + q][wave] = dp[q];
  }
  __syncthreads();
  if (tid < 16)
    durp[m0 + tid] = expf(dred[tid][0] + dred[tid][1] + dred[tid][2] + dred[tid][3] + bl[0]);
}

// ========== kernel C: length regulator, src-table driven, zero LDS ==========
__global__ __launch_bounds__(256) void lr_kernel(const float* __restrict__ x,
    const int* __restrict__ src,
    float* __restrict__ out0, float* __restrict__ alignp){
  int row  = blockIdx.x * 4 + (threadIdx.x >> 6);
  int lane = threadIdx.x & 63;
  int b = row >> 12;
  int s = __builtin_amdgcn_readfirstlane(src[row]);
  size_t orow = (size_t)row * 256;
  size_t arow = (size_t)row * 512;
  f32x4 z = {0.f, 0.f, 0.f, 0.f};
  if (s < 0){
    *reinterpret_cast<f32x4*>(out0 + orow + lane * 4) = z;
    *reinterpret_cast<f32x4*>(alignp + arow + lane * 8) = z;
    *reinterpret_cast<f32x4*>(alignp + arow + lane * 8 + 4) = z;
    return;
  }
  const f32x4 v = *reinterpret_cast<const f32x4*>(x + ((size_t)b * TENC + s) * DCH + lane * 4);
  *reinterpret_cast<f32x4*>(out0 + orow + lane * 4) = v;
  f32x4 a0 = z, a1 = z;
  int rel = s - lane * 8;
  if (rel >= 0 && rel < 8){
    if (rel < 4) a0[rel] = 1.0f; else a1[rel - 4] = 1.0f;
  }
  *reinterpret_cast<f32x4*>(alignp + arow + lane * 8) = a0;
  *reinterpret_cast<f32x4*>(alignp + arow + lane * 8 + 4) = a1;
}

extern "C" void kernel_launch(void* const* d_in, const int* in_sizes, int n_in,
                              void* d_out, int out_size, void* d_ws, size_t ws_size,
                              hipStream_t stream){
  const float* x   = (const float*)d_in[0];
  const int*   target = (const int*)d_in[1];
  const float* w1  = (const float*)d_in[2];
  const float* b1  = (const float*)d_in[3];
  const float* g1  = (const float*)d_in[4];
  const float* be1 = (const float*)d_in[5];
  const float* w2  = (const float*)d_in[6];
  const float* b2  = (const float*)d_in[7];
  const float* g2  = (const float*)d_in[8];
  const float* be2 = (const float*)d_in[9];
  const float* wl  = (const float*)d_in[10];
  const float* bl  = (const float*)d_in[11];

  float* out0   = (float*)d_out;
  float* alignp = out0 + (size_t)NB * TMEL * DCH;
  float* durp   = alignp + (size_t)NB * TMEL * TENC;

  char* ws = (char*)d_ws;
  int* cum   = (int*)ws;                                    // 32 KB
  int* total = (int*)(ws + 32768);
  int* src   = (int*)(ws + 65536);                          // 256 KB
  unsigned short* xb  = (unsigned short*)(ws + 65536 + 262144);            // 4 MB
  unsigned short* w1p = (unsigned short*)(ws + 65536 + 262144 + 4194304);  // 384 KB
  unsigned short* w2p = (unsigned short*)(ws + 65536 + 262144 + 4194304 + 393216);

  prep_scan_kernel<<<2832, 256, 0, stream>>>(x, target, w1, w2,
      (unsigned*)xb, w1p, w2p, cum, total, src);
  conv_fused_kernel<<<512, 256, 0, stream>>>(xb, w1p, w2p,
      b1, g1, be1, b2, g2, be2, wl, bl, durp);
  lr_kernel<<<NB * TMEL / 4, 256, 0, stream>>>(x, src, out0, alignp);
}

// Round 7
// 65.053 us; speedup vs baseline: 2.3793x; 1.2334x over previous
//
#include <hip/hip_runtime.h>

typedef __attribute__((ext_vector_type(8))) short short8;
typedef __attribute__((ext_vector_type(4))) float f32x4;

#define NB   16
#define TENC 512
#define DCH  256
#define TMEL 4096
#define ROWS (NB*TENC)   // 8192

__device__ __forceinline__ unsigned short f2bf(float f){
  unsigned u = __builtin_bit_cast(unsigned, f);
  u += 0x7FFFu + ((u >> 16) & 1u);
  return (unsigned short)(u >> 16);
}

// ========== kernel A: scan+src-table (blocks 0..15) + x->bf16 cast
// (blocks 16..2063, float4) + weight pack (blocks 2064..2831) ==========
__global__ __launch_bounds__(256) void prep_scan_kernel(
    const float* __restrict__ x, const int* __restrict__ target,
    const float* __restrict__ w1, const float* __restrict__ w2,
    unsigned* __restrict__ xb32,
    unsigned short* __restrict__ w1p, unsigned short* __restrict__ w2p,
    int* __restrict__ cum, int* __restrict__ total, int* __restrict__ src){
  __shared__ int wsum[4];
  __shared__ int stot;
  int bid = blockIdx.x, tid = threadIdx.x;
  if (bid < 16){
    int lane = tid & 63, wv = tid >> 6;
    int a0 = target[bid * 512 + 2 * tid];
    int a1 = target[bid * 512 + 2 * tid + 1];
    int ps = a0 + a1;
    #pragma unroll
    for (int off = 1; off < 64; off <<= 1){
      int v = __shfl_up(ps, off);
      if (lane >= off) ps += v;
    }
    if (lane == 63) wsum[wv] = ps;
    __syncthreads();
    int add = 0;
    #pragma unroll
    for (int w = 0; w < 4; ++w){ int s = wsum[w]; if (w < wv) add += s; }
    ps += add;
    int c1 = ps;            // cum[2tid+1]
    int c0 = ps - a1;       // cum[2tid]
    int cp = c0 - a0;       // cum[2tid-1]
    cum[bid * 512 + 2 * tid]     = c0;
    cum[bid * 512 + 2 * tid + 1] = c1;
    if (tid == 255){ total[bid] = c1; stot = c1; }
    int* sb = src + bid * TMEL;
    for (int t = cp; t < c0; ++t) sb[t] = 2 * tid;
    for (int t = c0; t < c1; ++t) sb[t] = 2 * tid + 1;
    __syncthreads();
    for (int t = stot + tid; t < TMEL; t += 256) sb[t] = -1;
  } else if (bid < 16 + 2048){
    int i = (bid - 16) * 256 + tid;          // handles x[4i..4i+3]
    const f32x4 v = *reinterpret_cast<const f32x4*>(x + 4 * (size_t)i);
    unsigned lo = (unsigned)f2bf(v.x) | ((unsigned)f2bf(v.y) << 16);
    unsigned hi = (unsigned)f2bf(v.z) | ((unsigned)f2bf(v.w) << 16);
    xb32[2 * i]     = lo;
    xb32[2 * i + 1] = hi;
  } else {
    int i = (bid - 16 - 2048) * 256 + tid;   // 0..196607
    int j = i & 7, lane = (i >> 3) & 63, nt = (i >> 9) & 15, ks = i >> 13;
    int r   = ks * 32 + ((lane >> 4) * 8) + j;
    int col = nt * 16 + (lane & 15);
    w1p[i] = f2bf(w1[r * 256 + col]);
    w2p[i] = f2bf(w2[r * 256 + col]);
  }
}

// ========== kernel B (fused): blocks 0..511 conv1+conv2+dur (16 rows each),
// blocks 512.. length-regulator (4 rows each). VGPR capped via
// __launch_bounds__(256,4) -> <=128 VGPR -> LR blocks get 16 waves/CU. ==========
__global__ __launch_bounds__(256, 4) void fused_kernel(
    const float* __restrict__ x, const int* __restrict__ src,
    const unsigned short* __restrict__ xb,
    const unsigned short* __restrict__ w1p, const unsigned short* __restrict__ w2p,
    const float* __restrict__ b1, const float* __restrict__ g1, const float* __restrict__ be1,
    const float* __restrict__ b2, const float* __restrict__ g2, const float* __restrict__ be2,
    const float* __restrict__ wl, const float* __restrict__ bl,
    float* __restrict__ out0, float* __restrict__ alignp, float* __restrict__ durp)
{
  __shared__ unsigned short hsw[48 * 256];   // swizzled h tile, 24 KB
  __shared__ float red[48][4][2];
  __shared__ float dred[16][4];
  int tid = threadIdx.x;

  if (blockIdx.x >= 512){
    // ---------------- length regulator ----------------
    int row  = (blockIdx.x - 512) * 4 + (tid >> 6);
    int lane = tid & 63;
    int b = row >> 12;
    int s = __builtin_amdgcn_readfirstlane(src[row]);
    size_t orow = (size_t)row * 256;
    size_t arow = (size_t)row * 512;
    f32x4 z = {0.f, 0.f, 0.f, 0.f};
    if (s < 0){
      *reinterpret_cast<f32x4*>(out0 + orow + lane * 4) = z;
      *reinterpret_cast<f32x4*>(alignp + arow + lane * 8) = z;
      *reinterpret_cast<f32x4*>(alignp + arow + lane * 8 + 4) = z;
      return;
    }
    const f32x4 v = *reinterpret_cast<const f32x4*>(x + ((size_t)b * TENC + s) * DCH + lane * 4);
    *reinterpret_cast<f32x4*>(out0 + orow + lane * 4) = v;
    f32x4 a0 = z, a1 = z;
    int rel = s - lane * 8;
    if (rel >= 0 && rel < 8){
      if (rel < 4) a0[rel] = 1.0f; else a1[rel - 4] = 1.0f;
    }
    *reinterpret_cast<f32x4*>(alignp + arow + lane * 8) = a0;
    *reinterpret_cast<f32x4*>(alignp + arow + lane * 8 + 4) = a1;
    return;
  }

  // ---------------- conv path: output rows [m0, m0+16) ----------------
  int m0 = blockIdx.x * 16;
  int rowlo = (m0 >> 9) << 9, rowhi = rowlo + 512;
  int wave = tid >> 6, l = tid & 63, kgrp = l >> 4, l16 = l & 15;
  int colb = wave * 64 + l16;

  // ---- phase 1: conv1+LN+relu for h rows g = m0-16 .. m0+31 (3 tiles) ----
  f32x4 acc[3][4];
  #pragma unroll
  for (int mt = 0; mt < 3; ++mt)
    #pragma unroll
    for (int nt = 0; nt < 4; ++nt) acc[mt][nt] = (f32x4)0.0f;

  for (int ks = 0; ks < 24; ++ks){
    int shift = ks >> 3;
    int c = (ks & 7) * 32 + kgrp * 8;
    const unsigned short* wb = w1p + (size_t)(ks * 16 + wave * 4) * 512 + l * 8;
    short8 bf0 = *reinterpret_cast<const short8*>(wb);
    short8 bf1 = *reinterpret_cast<const short8*>(wb + 512);
    short8 bf2 = *reinterpret_cast<const short8*>(wb + 1024);
    short8 bf3 = *reinterpret_cast<const short8*>(wb + 1536);
    #pragma unroll
    for (int mt = 0; mt < 3; ++mt){
      int grow = m0 - 16 + mt * 16 + l16 + shift - 1;
      short8 a = {0,0,0,0,0,0,0,0};
      if (grow >= rowlo && grow < rowhi)
        a = *reinterpret_cast<const short8*>(xb + (size_t)grow * 256 + c);
      acc[mt][0] = __builtin_amdgcn_mfma_f32_16x16x32_bf16(a, bf0, acc[mt][0], 0, 0, 0);
      acc[mt][1] = __builtin_amdgcn_mfma_f32_16x16x32_bf16(a, bf1, acc[mt][1], 0, 0, 0);
      acc[mt][2] = __builtin_amdgcn_mfma_f32_16x16x32_bf16(a, bf2, acc[mt][2], 0, 0, 0);
      acc[mt][3] = __builtin_amdgcn_mfma_f32_16x16x32_bf16(a, bf3, acc[mt][3], 0, 0, 0);
    }
  }
  #pragma unroll
  for (int mt = 0; mt < 3; ++mt){
    float s1[4] = {0,0,0,0}, s2[4] = {0,0,0,0};
    #pragma unroll
    for (int nt = 0; nt < 4; ++nt){
      float bv = b1[colb + nt * 16];
      #pragma unroll
      for (int q = 0; q < 4; ++q){
        float v = acc[mt][nt][q] + bv;
        acc[mt][nt][q] = v;
        s1[q] += v; s2[q] += v * v;
      }
    }
    #pragma unroll
    for (int m = 1; m < 16; m <<= 1)
      #pragma unroll
      for (int q = 0; q < 4; ++q){
        s1[q] += __shfl_xor(s1[q], m);
        s2[q] += __shfl_xor(s2[q], m);
      }
    if (l16 == 0)
      #pragma unroll
      for (int q = 0; q < 4; ++q){
        red[mt * 16 + kgrp * 4 + q][wave][0] = s1[q];
        red[mt * 16 + kgrp * 4 + q][wave][1] = s2[q];
      }
  }
  __syncthreads();
  float mu[3][4], rs[3][4];
  #pragma unroll
  for (int mt = 0; mt < 3; ++mt)
    #pragma unroll
    for (int q = 0; q < 4; ++q){
      int r = mt * 16 + kgrp * 4 + q;
      float S1 = red[r][0][0] + red[r][1][0] + red[r][2][0] + red[r][3][0];
      float S2 = red[r][0][1] + red[r][1][1] + red[r][2][1] + red[r][3][1];
      float m_ = S1 * (1.0f / 256.0f);
      float var = S2 * (1.0f / 256.0f) - m_ * m_;
      mu[mt][q] = m_;
      rs[mt][q] = rsqrtf(var + 1e-5f);
    }
  #pragma unroll
  for (int mt = 0; mt < 3; ++mt)
    #pragma unroll
    for (int nt = 0; nt < 4; ++nt){
      int col = colb + nt * 16;
      float g = g1[col], be = be1[col];
      #pragma unroll
      for (int q = 0; q < 4; ++q){
        int r = mt * 16 + kgrp * 4 + q;
        int gq = m0 - 16 + r;
        float y = fmaxf((acc[mt][nt][q] - mu[mt][q]) * rs[mt][q] * g + be, 0.0f);
        unsigned short hv = (gq >= rowlo && gq < rowhi) ? f2bf(y) : (unsigned short)0;
        hsw[r * 256 + (col ^ ((r & 7) << 3))] = hv;
      }
    }
  __syncthreads();

  // ---- phase 2: conv2 (A from LDS) + LN + relu + dot(wl) + exp ----
  f32x4 acc2[4];
  #pragma unroll
  for (int nt = 0; nt < 4; ++nt) acc2[nt] = (f32x4)0.0f;

  for (int ks = 0; ks < 24; ++ks){
    int shift = ks >> 3;
    int c = (ks & 7) * 32 + kgrp * 8;
    const unsigned short* wb = w2p + (size_t)(ks * 16 + wave * 4) * 512 + l * 8;
    short8 bf0 = *reinterpret_cast<const short8*>(wb);
    short8 bf1 = *reinterpret_cast<const short8*>(wb + 512);
    short8 bf2 = *reinterpret_cast<const short8*>(wb + 1024);
    short8 bf3 = *reinterpret_cast<const short8*>(wb + 1536);
    int rr = 16 + l16 + shift - 1;   // 15..31, inside 48-row tile
    short8 a = *reinterpret_cast<const short8*>(hsw + rr * 256 + (c ^ ((rr & 7) << 3)));
    acc2[0] = __builtin_amdgcn_mfma_f32_16x16x32_bf16(a, bf0, acc2[0], 0, 0, 0);
    acc2[1] = __builtin_amdgcn_mfma_f32_16x16x32_bf16(a, bf1, acc2[1], 0, 0, 0);
    acc2[2] = __builtin_amdgcn_mfma_f32_16x16x32_bf16(a, bf2, acc2[2], 0, 0, 0);
    acc2[3] = __builtin_amdgcn_mfma_f32_16x16x32_bf16(a, bf3, acc2[3], 0, 0, 0);
  }
  __syncthreads();
  {
    float s1[4] = {0,0,0,0}, s2[4] = {0,0,0,0};
    #pragma unroll
    for (int nt = 0; nt < 4; ++nt){
      float bv = b2[colb + nt * 16];
      #pragma unroll
      for (int q = 0; q < 4; ++q){
        float v = acc2[nt][q] + bv;
        acc2[nt][q] = v;
        s1[q] += v; s2[q] += v * v;
      }
    }
    #pragma unroll
    for (int m = 1; m < 16; m <<= 1)
      #pragma unroll
      for (int q = 0; q < 4; ++q){
        s1[q] += __shfl_xor(s1[q], m);
        s2[q] += __shfl_xor(s2[q], m);
      }
    if (l16 == 0)
      #pragma unroll
      for (int q = 0; q < 4; ++q){
        red[kgrp * 4 + q][wave][0] = s1[q];
        red[kgrp * 4 + q][wave][1] = s2[q];
      }
  }
  __syncthreads();
  {
    float mu2[4], rs2[4];
    #pragma unroll
    for (int q = 0; q < 4; ++q){
      int r = kgrp * 4 + q;
      float S1 = red[r][0][0] + red[r][1][0] + red[r][2][0] + red[r][3][0];
      float S2 = red[r][0][1] + red[r][1][1] + red[r][2][1] + red[r][3][1];
      float m_ = S1 * (1.0f / 256.0f);
      float var = S2 * (1.0f / 256.0f) - m_ * m_;
      mu2[q] = m_;
      rs2[q] = rsqrtf(var + 1e-5f);
    }
    float dp[4] = {0,0,0,0};
    #pragma unroll
    for (int nt = 0; nt < 4; ++nt){
      int col = colb + nt * 16;
      float g = g2[col], be = be2[col], wv = wl[col];
      #pragma unroll
      for (int q = 0; q < 4; ++q){
        float y = fmaxf((acc2[nt][q] - mu2[q]) * rs2[q] * g + be, 0.0f);
        dp[q] += y * wv;
      }
    }
    #pragma unroll
    for (int m = 1; m < 16; m <<= 1)
      #pragma unroll
      for (int q = 0; q < 4; ++q) dp[q] += __shfl_xor(dp[q], m);
    if (l16 == 0)
      #pragma unroll
      for (int q = 0; q < 4; ++q) dred[kgrp * 4 + q][wave] = dp[q];
  }
  __syncthreads();
  if (tid < 16)
    durp[m0 + tid] = expf(dred[tid][0] + dred[tid][1] + dred[tid][2] + dred[tid][3] + bl[0]);
}

extern "C" void kernel_launch(void* const* d_in, const int* in_sizes, int n_in,
                              void* d_out, int out_size, void* d_ws, size_t ws_size,
                              hipStream_t stream){
  const float* x   = (const float*)d_in[0];
  const int*   target = (const int*)d_in[1];
  const float* w1  = (const float*)d_in[2];
  const float* b1  = (const float*)d_in[3];
  const float* g1  = (const float*)d_in[4];
  const float* be1 = (const float*)d_in[5];
  const float* w2  = (const float*)d_in[6];
  const float* b2  = (const float*)d_in[7];
  const float* g2  = (const float*)d_in[8];
  const float* be2 = (const float*)d_in[9];
  const float* wl  = (const float*)d_in[10];
  const float* bl  = (const float*)d_in[11];

  float* out0   = (float*)d_out;
  float* alignp = out0 + (size_t)NB * TMEL * DCH;
  float* durp   = alignp + (size_t)NB * TMEL * TENC;

  char* ws = (char*)d_ws;
  int* cum   = (int*)ws;                                    // 32 KB
  int* total = (int*)(ws + 32768);
  int* src   = (int*)(ws + 65536);                          // 256 KB
  unsigned short* xb  = (unsigned short*)(ws + 65536 + 262144);            // 4 MB
  unsigned short* w1p = (unsigned short*)(ws + 65536 + 262144 + 4194304);  // 384 KB
  unsigned short* w2p = (unsigned short*)(ws + 65536 + 262144 + 4194304 + 393216);

  prep_scan_kernel<<<2832, 256, 0, stream>>>(x, target, w1, w2,
      (unsigned*)xb, w1p, w2p, cum, total, src);
  fused_kernel<<<512 + NB * TMEL / 4, 256, 0, stream>>>(x, src, xb, w1p, w2p,
      b1, g1, be1, b2, g2, be2, wl, bl, out0, alignp, durp);
}

// Round 8
// 52.627 us; speedup vs baseline: 2.9411x; 1.2361x over previous
//
#include <hip/hip_runtime.h>

typedef __attribute__((ext_vector_type(8))) short short8;
typedef __attribute__((ext_vector_type(4))) float f32x4;
typedef __attribute__((ext_vector_type(2))) unsigned u32x2;

#define NB   16
#define TENC 512
#define DCH  256
#define TMEL 4096
#define ROWS (NB*TENC)   // 8192

__device__ __forceinline__ unsigned short f2bf(float f){
  unsigned u = __builtin_bit_cast(unsigned, f);
  u += 0x7FFFu + ((u >> 16) & 1u);
  return (unsigned short)(u >> 16);
}

// ========== kernel A: scan+src-table (blocks 0..15) +
// weight pack, read-coalesced (blocks 16..783) ==========
__global__ __launch_bounds__(256) void prep_scan_kernel(
    const int* __restrict__ target,
    const float* __restrict__ w1, const float* __restrict__ w2,
    unsigned short* __restrict__ w1p, unsigned short* __restrict__ w2p,
    int* __restrict__ src){
  __shared__ int wsum[4];
  __shared__ int stot;
  int bid = blockIdx.x, tid = threadIdx.x;
  if (bid < 16){
    int lane = tid & 63, wv = tid >> 6;
    int a0 = target[bid * 512 + 2 * tid];
    int a1 = target[bid * 512 + 2 * tid + 1];
    int ps = a0 + a1;
    #pragma unroll
    for (int off = 1; off < 64; off <<= 1){
      int v = __shfl_up(ps, off);
      if (lane >= off) ps += v;
    }
    if (lane == 63) wsum[wv] = ps;
    __syncthreads();
    int add = 0;
    #pragma unroll
    for (int w = 0; w < 4; ++w){ int s = wsum[w]; if (w < wv) add += s; }
    ps += add;
    int c1 = ps;            // cum[2tid+1]
    int c0 = ps - a1;       // cum[2tid]
    int cp = c0 - a0;       // cum[2tid-1]
    if (tid == 255) stot = c1;
    int* sb = src + bid * TMEL;
    for (int t = cp; t < c0; ++t) sb[t] = 2 * tid;
    for (int t = c0; t < c1; ++t) sb[t] = 2 * tid + 1;
    __syncthreads();
    for (int t = stot + tid; t < TMEL; t += 256) sb[t] = -1;
  } else {
    // read w[i] coalesced, scatter into fragment layout
    int i = (bid - 16) * 256 + tid;          // 0..196607
    int r = i >> 8, col = i & 255;
    int ks = r >> 5, rh = (r >> 3) & 3, j = r & 7;
    int nt = col >> 4, lane = rh * 16 + (col & 15);
    int o = (((ks << 4) + nt) << 9) + (lane << 3) + j;
    w1p[o] = f2bf(w1[i]);
    w2p[o] = f2bf(w2[i]);
  }
}

// ========== kernel B (fused): blocks 0..511 conv (16 out rows each),
// blocks 512.. length-regulator (4 rows each). ==========
__global__ __launch_bounds__(256, 4) void fused_kernel(
    const float* __restrict__ x, const int* __restrict__ src,
    const unsigned short* __restrict__ w1p, const unsigned short* __restrict__ w2p,
    const float* __restrict__ b1, const float* __restrict__ g1, const float* __restrict__ be1,
    const float* __restrict__ b2, const float* __restrict__ g2, const float* __restrict__ be2,
    const float* __restrict__ wl, const float* __restrict__ bl,
    float* __restrict__ out0, float* __restrict__ alignp, float* __restrict__ durp)
{
  __shared__ unsigned short xsw[34 * 256];   // swizzled x tile (bf16), 17 KB
  __shared__ unsigned short hsw[32 * 256];   // swizzled h tile, 16 KB
  __shared__ float red[32][4][2];
  __shared__ float dred[16][4];
  int tid = threadIdx.x;

  if (blockIdx.x >= 512){
    // ---------------- length regulator ----------------
    int row  = (blockIdx.x - 512) * 4 + (tid >> 6);
    int lane = tid & 63;
    int b = row >> 12;
    int s = __builtin_amdgcn_readfirstlane(src[row]);
    size_t orow = (size_t)row * 256;
    size_t arow = (size_t)row * 512;
    f32x4 z = {0.f, 0.f, 0.f, 0.f};
    if (s < 0){
      *reinterpret_cast<f32x4*>(out0 + orow + lane * 4) = z;
      *reinterpret_cast<f32x4*>(alignp + arow + lane * 8) = z;
      *reinterpret_cast<f32x4*>(alignp + arow + lane * 8 + 4) = z;
      return;
    }
    const f32x4 v = *reinterpret_cast<const f32x4*>(x + ((size_t)b * TENC + s) * DCH + lane * 4);
    *reinterpret_cast<f32x4*>(out0 + orow + lane * 4) = v;
    f32x4 a0 = z, a1 = z;
    int rel = s - lane * 8;
    if (rel >= 0 && rel < 8){
      if (rel < 4) a0[rel] = 1.0f; else a1[rel - 4] = 1.0f;
    }
    *reinterpret_cast<f32x4*>(alignp + arow + lane * 8) = a0;
    *reinterpret_cast<f32x4*>(alignp + arow + lane * 8 + 4) = a1;
    return;
  }

  // ---------------- conv path: output rows [m0, m0+16) ----------------
  int m0 = blockIdx.x * 16;
  int rowlo = (m0 >> 9) << 9, rowhi = rowlo + 512;
  int wave = tid >> 6, l = tid & 63, kgrp = l >> 4, l16 = l & 15;
  int colb = wave * 64 + l16;

  // ---- phase 0: load x rows m0-2 .. m0+31 (34 rows) as bf16 into swizzled LDS ----
  {
    int lane = l;
    #pragma unroll
    for (int it = 0; it < 9; ++it){
      int rr = it * 4 + wave;
      if (rr < 34){
        int grow = m0 - 2 + rr;
        f32x4 v = {0.f, 0.f, 0.f, 0.f};
        if (grow >= rowlo && grow < rowhi)
          v = *reinterpret_cast<const f32x4*>(x + (size_t)grow * 256 + lane * 4);
        unsigned lo = (unsigned)f2bf(v.x) | ((unsigned)f2bf(v.y) << 16);
        unsigned hi = (unsigned)f2bf(v.z) | ((unsigned)f2bf(v.w) << 16);
        int col = lane * 4;
        u32x2 pk = {lo, hi};
        *reinterpret_cast<u32x2*>(xsw + rr * 256 + (col ^ ((rr & 7) << 3))) = pk;
      }
    }
  }
  __syncthreads();

  // ---- phase 1: conv1+LN+relu for h rows m0-1 .. m0+30 (2 unaligned tiles) ----
  f32x4 acc[2][4];
  #pragma unroll
  for (int mt = 0; mt < 2; ++mt)
    #pragma unroll
    for (int nt = 0; nt < 4; ++nt) acc[mt][nt] = (f32x4)0.0f;

  for (int ks = 0; ks < 24; ++ks){
    int shift = ks >> 3;
    int c = (ks & 7) * 32 + kgrp * 8;
    const unsigned short* wb = w1p + (size_t)(ks * 16 + wave * 4) * 512 + l * 8;
    short8 bf0 = *reinterpret_cast<const short8*>(wb);
    short8 bf1 = *reinterpret_cast<const short8*>(wb + 512);
    short8 bf2 = *reinterpret_cast<const short8*>(wb + 1024);
    short8 bf3 = *reinterpret_cast<const short8*>(wb + 1536);
    #pragma unroll
    for (int mt = 0; mt < 2; ++mt){
      int rr = mt * 16 + l16 + shift;   // xsw row for h-row (m0-1+mt*16+l16) + tap shift - 1
      short8 a = *reinterpret_cast<const short8*>(xsw + rr * 256 + (c ^ ((rr & 7) << 3)));
      acc[mt][0] = __builtin_amdgcn_mfma_f32_16x16x32_bf16(a, bf0, acc[mt][0], 0, 0, 0);
      acc[mt][1] = __builtin_amdgcn_mfma_f32_16x16x32_bf16(a, bf1, acc[mt][1], 0, 0, 0);
      acc[mt][2] = __builtin_amdgcn_mfma_f32_16x16x32_bf16(a, bf2, acc[mt][2], 0, 0, 0);
      acc[mt][3] = __builtin_amdgcn_mfma_f32_16x16x32_bf16(a, bf3, acc[mt][3], 0, 0, 0);
    }
  }
  #pragma unroll
  for (int mt = 0; mt < 2; ++mt){
    float s1[4] = {0,0,0,0}, s2[4] = {0,0,0,0};
    #pragma unroll
    for (int nt = 0; nt < 4; ++nt){
      float bv = b1[colb + nt * 16];
      #pragma unroll
      for (int q = 0; q < 4; ++q){
        float v = acc[mt][nt][q] + bv;
        acc[mt][nt][q] = v;
        s1[q] += v; s2[q] += v * v;
      }
    }
    #pragma unroll
    for (int m = 1; m < 16; m <<= 1)
      #pragma unroll
      for (int q = 0; q < 4; ++q){
        s1[q] += __shfl_xor(s1[q], m);
        s2[q] += __shfl_xor(s2[q], m);
      }
    if (l16 == 0)
      #pragma unroll
      for (int q = 0; q < 4; ++q){
        red[mt * 16 + kgrp * 4 + q][wave][0] = s1[q];
        red[mt * 16 + kgrp * 4 + q][wave][1] = s2[q];
      }
  }
  __syncthreads();
  float mu[2][4], rs[2][4];
  #pragma unroll
  for (int mt = 0; mt < 2; ++mt)
    #pragma unroll
    for (int q = 0; q < 4; ++q){
      int r = mt * 16 + kgrp * 4 + q;
      float S1 = red[r][0][0] + red[r][1][0] + red[r][2][0] + red[r][3][0];
      float S2 = red[r][0][1] + red[r][1][1] + red[r][2][1] + red[r][3][1];
      float m_ = S1 * (1.0f / 256.0f);
      float var = S2 * (1.0f / 256.0f) - m_ * m_;
      mu[mt][q] = m_;
      rs[mt][q] = rsqrtf(var + 1e-5f);
    }
  #pragma unroll
  for (int mt = 0; mt < 2; ++mt)
    #pragma unroll
    for (int nt = 0; nt < 4; ++nt){
      int col = colb + nt * 16;
      float g = g1[col], be = be1[col];
      #pragma unroll
      for (int q = 0; q < 4; ++q){
        int r = mt * 16 + kgrp * 4 + q;
        int gq = m0 - 1 + r;
        float y = fmaxf((acc[mt][nt][q] - mu[mt][q]) * rs[mt][q] * g + be, 0.0f);
        unsigned short hv = (gq >= rowlo && gq < rowhi) ? f2bf(y) : (unsigned short)0;
        hsw[r * 256 + (col ^ ((r & 7) << 3))] = hv;
      }
    }
  __syncthreads();

  // ---- phase 2: conv2 (A from LDS) + LN + relu + dot(wl) + exp ----
  f32x4 acc2[4];
  #pragma unroll
  for (int nt = 0; nt < 4; ++nt) acc2[nt] = (f32x4)0.0f;

  for (int ks = 0; ks < 24; ++ks){
    int shift = ks >> 3;
    int c = (ks & 7) * 32 + kgrp * 8;
    const unsigned short* wb = w2p + (size_t)(ks * 16 + wave * 4) * 512 + l * 8;
    short8 bf0 = *reinterpret_cast<const short8*>(wb);
    short8 bf1 = *reinterpret_cast<const short8*>(wb + 512);
    short8 bf2 = *reinterpret_cast<const short8*>(wb + 1024);
    short8 bf3 = *reinterpret_cast<const short8*>(wb + 1536);
    int rr = l16 + shift;   // hsw row for h-row (m0+l16) + shift - 1; 0..17
    short8 a = *reinterpret_cast<const short8*>(hsw + rr * 256 + (c ^ ((rr & 7) << 3)));
    acc2[0] = __builtin_amdgcn_mfma_f32_16x16x32_bf16(a, bf0, acc2[0], 0, 0, 0);
    acc2[1] = __builtin_amdgcn_mfma_f32_16x16x32_bf16(a, bf1, acc2[1], 0, 0, 0);
    acc2[2] = __builtin_amdgcn_mfma_f32_16x16x32_bf16(a, bf2, acc2[2], 0, 0, 0);
    acc2[3] = __builtin_amdgcn_mfma_f32_16x16x32_bf16(a, bf3, acc2[3], 0, 0, 0);
  }
  __syncthreads();
  {
    float s1[4] = {0,0,0,0}, s2[4] = {0,0,0,0};
    #pragma unroll
    for (int nt = 0; nt < 4; ++nt){
      float bv = b2[colb + nt * 16];
      #pragma unroll
      for (int q = 0; q < 4; ++q){
        float v = acc2[nt][q] + bv;
        acc2[nt][q] = v;
        s1[q] += v; s2[q] += v * v;
      }
    }
    #pragma unroll
    for (int m = 1; m < 16; m <<= 1)
      #pragma unroll
      for (int q = 0; q < 4; ++q){
        s1[q] += __shfl_xor(s1[q], m);
        s2[q] += __shfl_xor(s2[q], m);
      }
    if (l16 == 0)
      #pragma unroll
      for (int q = 0; q < 4; ++q){
        red[kgrp * 4 + q][wave][0] = s1[q];
        red[kgrp * 4 + q][wave][1] = s2[q];
      }
  }
  __syncthreads();
  {
    float mu2[4], rs2[4];
    #pragma unroll
    for (int q = 0; q < 4; ++q){
      int r = kgrp * 4 + q;
      float S1 = red[r][0][0] + red[r][1][0] + red[r][2][0] + red[r][3][0];
      float S2 = red[r][0][1] + red[r][1][1] + red[r][2][1] + red[r][3][1];
      float m_ = S1 * (1.0f / 256.0f);
      float var = S2 * (1.0f / 256.0f) - m_ * m_;
      mu2[q] = m_;
      rs2[q] = rsqrtf(var + 1e-5f);
    }
    float dp[4] = {0,0,0,0};
    #pragma unroll
    for (int nt = 0; nt < 4; ++nt){
      int col = colb + nt * 16;
      float g = g2[col], be = be2[col], wv = wl[col];
      #pragma unroll
      for (int q = 0; q < 4; ++q){
        float y = fmaxf((acc2[nt][q] - mu2[q]) * rs2[q] * g + be, 0.0f);
        dp[q] += y * wv;
      }
    }
    #pragma unroll
    for (int m = 1; m < 16; m <<= 1)
      #pragma unroll
      for (int q = 0; q < 4; ++q) dp[q] += __shfl_xor(dp[q], m);
    if (l16 == 0)
      #pragma unroll
      for (int q = 0; q < 4; ++q) dred[kgrp * 4 + q][wave] = dp[q];
  }
  __syncthreads();
  if (tid < 16)
    durp[m0 + tid] = expf(dred[tid][0] + dred[tid][1] + dred[tid][2] + dred[tid][3] + bl[0]);
}

extern "C" void kernel_launch(void* const* d_in, const int* in_sizes, int n_in,
                              void* d_out, int out_size, void* d_ws, size_t ws_size,
                              hipStream_t stream){
  const float* x   = (const float*)d_in[0];
  const int*   target = (const int*)d_in[1];
  const float* w1  = (const float*)d_in[2];
  const float* b1  = (const float*)d_in[3];
  const float* g1  = (const float*)d_in[4];
  const float* be1 = (const float*)d_in[5];
  const float* w2  = (const float*)d_in[6];
  const float* b2  = (const float*)d_in[7];
  const float* g2  = (const float*)d_in[8];
  const float* be2 = (const float*)d_in[9];
  const float* wl  = (const float*)d_in[10];
  const float* bl  = (const float*)d_in[11];

  float* out0   = (float*)d_out;
  float* alignp = out0 + (size_t)NB * TMEL * DCH;
  float* durp   = alignp + (size_t)NB * TMEL * TENC;

  char* ws = (char*)d_ws;
  int* src = (int*)ws;                                         // 256 KB
  unsigned short* w1p = (unsigned short*)(ws + 262144);        // 384 KB
  unsigned short* w2p = (unsigned short*)(ws + 262144 + 393216);

  prep_scan_kernel<<<784, 256, 0, stream>>>(target, w1, w2, w1p, w2p, src);
  fused_kernel<<<512 + NB * TMEL / 4, 256, 0, stream>>>(x, src, w1p, w2p,
      b1, g1, be1, b2, g2, be2, wl, bl, out0, alignp, durp);
}